// Round 1
// baseline (1070.710 us; speedup 1.0000x reference)
//
#include <hip/hip_runtime.h>
#include <hip/hip_bf16.h>

#define N_NODES 50000
#define N_EDGES 1000000
#define DIM 64
#define N_GRAPHS 64
#define OUT_DIM 8

// ---------------------------------------------------------------------------
// Edge scatter: one wave (64 lanes) per edge; lane j handles feature j.
// agg[dst] += feat[src]; optionally deg[dst] += 1 (lane 0).
// ---------------------------------------------------------------------------
__global__ void scatter_kernel(const float* __restrict__ feat,
                               const int* __restrict__ src,
                               const int* __restrict__ dst,
                               float* __restrict__ agg,
                               float* __restrict__ deg,
                               int do_deg) {
    long long i = (long long)blockIdx.x * blockDim.x + threadIdx.x;
    const long long total = (long long)N_EDGES * DIM;
    if (i >= total) return;
    int e = (int)(i >> 6);
    int j = (int)(i & 63);
    int s = src[e];
    int d = dst[e];
    atomicAdd(&agg[(long long)d * DIM + j], feat[(long long)s * DIM + j]);
    if (do_deg && j == 0) atomicAdd(&deg[d], 1.0f);
}

// ---------------------------------------------------------------------------
// Node update: out[n][j] = act( (agg[n]/max(deg,1)) @ Wl + b + feat[n] @ Wr )
// Block = 256 threads = 4 nodes; W matrices staged in LDS (2 x 16 KiB).
// ---------------------------------------------------------------------------
__global__ void sage_update_kernel(const float* __restrict__ feat,
                                   const float* __restrict__ agg,
                                   const float* __restrict__ deg,
                                   const float* __restrict__ Wl,
                                   const float* __restrict__ b,
                                   const float* __restrict__ Wr,
                                   float* __restrict__ out,
                                   int relu_flag) {
    __shared__ float sWl[DIM * DIM];
    __shared__ float sWr[DIM * DIM];
    for (int i = threadIdx.x; i < DIM * DIM; i += blockDim.x) {
        sWl[i] = Wl[i];
        sWr[i] = Wr[i];
    }
    __syncthreads();

    int j = threadIdx.x & 63;
    int n = blockIdx.x * (blockDim.x >> 6) + (threadIdx.x >> 6);
    if (n >= N_NODES) return;

    float inv = 1.0f / fmaxf(deg[n], 1.0f);
    const float* aggrow = &agg[(long long)n * DIM];
    const float* xrow   = &feat[(long long)n * DIM];

    float sum = b[j];
    #pragma unroll
    for (int k = 0; k < DIM; ++k) {
        sum += aggrow[k] * inv * sWl[k * DIM + j];
        sum += xrow[k] * sWr[k * DIM + j];
    }
    if (relu_flag) sum = fmaxf(sum, 0.0f);
    out[(long long)n * DIM + j] = sum;
}

// ---------------------------------------------------------------------------
// Global mean pool (sum + count via atomics; batch ids in [0, N_GRAPHS))
// ---------------------------------------------------------------------------
__global__ void pool_kernel(const float* __restrict__ h,
                            const int* __restrict__ batch,
                            float* __restrict__ psum,
                            float* __restrict__ pcnt) {
    long long i = (long long)blockIdx.x * blockDim.x + threadIdx.x;
    const long long total = (long long)N_NODES * DIM;
    if (i >= total) return;
    int n = (int)(i >> 6);
    int j = (int)(i & 63);
    int g = batch[n];
    atomicAdd(&psum[g * DIM + j], h[i]);
    if (j == 0) atomicAdd(&pcnt[g], 1.0f);
}

// ---------------------------------------------------------------------------
// Final FC: out[g][o] = (psum[g]/max(cnt,1)) @ Wfc + bfc   (64 x 8)
// One block of 512 threads: thread = (g, o).
// ---------------------------------------------------------------------------
__global__ void fc_kernel(const float* __restrict__ psum,
                          const float* __restrict__ pcnt,
                          const float* __restrict__ Wfc,
                          const float* __restrict__ bfc,
                          float* __restrict__ out) {
    int tid = threadIdx.x;
    if (tid >= N_GRAPHS * OUT_DIM) return;
    int g = tid >> 3;
    int o = tid & 7;
    float inv = 1.0f / fmaxf(pcnt[g], 1.0f);
    float s = bfc[o];
    #pragma unroll
    for (int k = 0; k < DIM; ++k) {
        s += psum[g * DIM + k] * inv * Wfc[k * OUT_DIM + o];
    }
    out[g * OUT_DIM + o] = s;
}

extern "C" void kernel_launch(void* const* d_in, const int* in_sizes, int n_in,
                              void* d_out, int out_size, void* d_ws, size_t ws_size,
                              hipStream_t stream) {
    const float* x   = (const float*)d_in[0];
    const int* ei    = (const int*)d_in[1];
    const int* batch = (const int*)d_in[2];
    const float* W1l = (const float*)d_in[3];
    const float* b1  = (const float*)d_in[4];
    const float* W1r = (const float*)d_in[5];
    const float* W2l = (const float*)d_in[6];
    const float* b2  = (const float*)d_in[7];
    const float* W2r = (const float*)d_in[8];
    const float* Wfc = (const float*)d_in[9];
    const float* bfc = (const float*)d_in[10];
    float* out = (float*)d_out;

    const int* src = ei;
    const int* dst = ei + N_EDGES;

    // workspace layout (bytes, 256-aligned)
    const size_t SZ_FEAT = (size_t)N_NODES * DIM * sizeof(float); // 12.8 MB
    char* ws = (char*)d_ws;
    float* agg  = (float*)(ws);
    float* h1   = (float*)(ws + SZ_FEAT);
    float* h2   = (float*)(ws + 2 * SZ_FEAT);
    float* deg  = (float*)(ws + 3 * SZ_FEAT);
    float* psum = (float*)(ws + 3 * SZ_FEAT + 256 * 1024);
    float* pcnt = psum + N_GRAPHS * DIM;

    const int edgeThreads = 256;
    const int edgeBlocks = (int)(((long long)N_EDGES * DIM + edgeThreads - 1) / edgeThreads);
    const int nodeBlocks = (N_NODES + 3) / 4;  // 4 nodes per 256-thread block
    const int poolBlocks = (int)(((long long)N_NODES * DIM + 255) / 256);

    // ---- Layer 1 ----
    hipMemsetAsync(agg, 0, SZ_FEAT, stream);
    hipMemsetAsync(deg, 0, (size_t)N_NODES * sizeof(float), stream);
    hipMemsetAsync(psum, 0, (size_t)(N_GRAPHS * DIM + N_GRAPHS) * sizeof(float), stream);

    scatter_kernel<<<edgeBlocks, edgeThreads, 0, stream>>>(x, src, dst, agg, deg, 1);
    sage_update_kernel<<<nodeBlocks, 256, 0, stream>>>(x, agg, deg, W1l, b1, W1r, h1, 1);

    // ---- Layer 2 ----
    hipMemsetAsync(agg, 0, SZ_FEAT, stream);
    scatter_kernel<<<edgeBlocks, edgeThreads, 0, stream>>>(h1, src, dst, agg, deg, 0);
    sage_update_kernel<<<nodeBlocks, 256, 0, stream>>>(h1, agg, deg, W2l, b2, W2r, h2, 1);

    // ---- Pool + FC ----
    pool_kernel<<<poolBlocks, 256, 0, stream>>>(h2, batch, psum, pcnt);
    fc_kernel<<<1, 512, 0, stream>>>(psum, pcnt, Wfc, bfc, out);
}

// Round 2
// 688.950 us; speedup vs baseline: 1.5541x; 1.5541x over previous
//
#include <hip/hip_runtime.h>
#include <hip/hip_bf16.h>

#define N_NODES 50000
#define N_EDGES 1000000
#define DIM 64
#define N_GRAPHS 64
#define OUT_DIM 8
#define POOL_NODES_PER_WAVE 16

// ---------------------------------------------------------------------------
// Edge scatter: one wave (64 lanes) per edge; lane j handles feature j.
// agg[dst] += feat[src]; optionally deg[dst] += 1 (lane 0).
// ---------------------------------------------------------------------------
__global__ void scatter_kernel(const float* __restrict__ feat,
                               const int* __restrict__ src,
                               const int* __restrict__ dst,
                               float* __restrict__ agg,
                               float* __restrict__ deg,
                               int do_deg) {
    long long i = (long long)blockIdx.x * blockDim.x + threadIdx.x;
    const long long total = (long long)N_EDGES * DIM;
    if (i >= total) return;
    int e = (int)(i >> 6);
    int j = (int)(i & 63);
    int s = src[e];
    int d = dst[e];
    atomicAdd(&agg[(long long)d * DIM + j], feat[(long long)s * DIM + j]);
    if (do_deg && j == 0) atomicAdd(&deg[d], 1.0f);
}

// ---------------------------------------------------------------------------
// Node update: out[n][j] = act( (agg[n]/max(deg,1)) @ Wl + b + feat[n] @ Wr )
// Block = 256 threads = 4 nodes; W matrices staged in LDS (2 x 16 KiB).
// ---------------------------------------------------------------------------
__global__ void sage_update_kernel(const float* __restrict__ feat,
                                   const float* __restrict__ agg,
                                   const float* __restrict__ deg,
                                   const float* __restrict__ Wl,
                                   const float* __restrict__ b,
                                   const float* __restrict__ Wr,
                                   float* __restrict__ out,
                                   int relu_flag) {
    __shared__ float sWl[DIM * DIM];
    __shared__ float sWr[DIM * DIM];
    for (int i = threadIdx.x; i < DIM * DIM; i += blockDim.x) {
        sWl[i] = Wl[i];
        sWr[i] = Wr[i];
    }
    __syncthreads();

    int j = threadIdx.x & 63;
    int n = blockIdx.x * (blockDim.x >> 6) + (threadIdx.x >> 6);
    if (n >= N_NODES) return;

    float inv = 1.0f / fmaxf(deg[n], 1.0f);
    const float* aggrow = &agg[(long long)n * DIM];
    const float* xrow   = &feat[(long long)n * DIM];

    float sum = b[j];
    #pragma unroll
    for (int k = 0; k < DIM; ++k) {
        sum += aggrow[k] * inv * sWl[k * DIM + j];
        sum += xrow[k] * sWr[k * DIM + j];
    }
    if (relu_flag) sum = fmaxf(sum, 0.0f);
    out[(long long)n * DIM + j] = sum;
}

// ---------------------------------------------------------------------------
// Global mean pool — segmented reduction exploiting sorted batch ids.
// One wave handles POOL_NODES_PER_WAVE consecutive nodes; lane j = feature j.
// Register-accumulate while graph id constant; flush via atomic on change.
// Atomic count: ~N_NODES/POOL_NODES_PER_WAVE * 64 ≈ 210k (was 3.2M).
// ---------------------------------------------------------------------------
__global__ void pool_kernel(const float* __restrict__ h,
                            const int* __restrict__ batch,
                            float* __restrict__ psum,
                            float* __restrict__ pcnt) {
    int wave = blockIdx.x * (blockDim.x >> 6) + (threadIdx.x >> 6);
    int j = threadIdx.x & 63;
    int start = wave * POOL_NODES_PER_WAVE;
    if (start >= N_NODES) return;
    int end = start + POOL_NODES_PER_WAVE;
    if (end > N_NODES) end = N_NODES;

    int g = batch[start];
    float acc = 0.0f;
    float cnt = 0.0f;
    for (int n = start; n < end; ++n) {
        int gn = batch[n];
        if (gn != g) {
            atomicAdd(&psum[g * DIM + j], acc);
            if (j == 0) atomicAdd(&pcnt[g], cnt);
            g = gn;
            acc = 0.0f;
            cnt = 0.0f;
        }
        acc += h[(long long)n * DIM + j];
        cnt += 1.0f;
    }
    atomicAdd(&psum[g * DIM + j], acc);
    if (j == 0) atomicAdd(&pcnt[g], cnt);
}

// ---------------------------------------------------------------------------
// Final FC: out[g][o] = (psum[g]/max(cnt,1)) @ Wfc + bfc   (64 x 8)
// ---------------------------------------------------------------------------
__global__ void fc_kernel(const float* __restrict__ psum,
                          const float* __restrict__ pcnt,
                          const float* __restrict__ Wfc,
                          const float* __restrict__ bfc,
                          float* __restrict__ out) {
    int tid = threadIdx.x;
    if (tid >= N_GRAPHS * OUT_DIM) return;
    int g = tid >> 3;
    int o = tid & 7;
    float inv = 1.0f / fmaxf(pcnt[g], 1.0f);
    float s = bfc[o];
    #pragma unroll
    for (int k = 0; k < DIM; ++k) {
        s += psum[g * DIM + k] * inv * Wfc[k * OUT_DIM + o];
    }
    out[g * OUT_DIM + o] = s;
}

extern "C" void kernel_launch(void* const* d_in, const int* in_sizes, int n_in,
                              void* d_out, int out_size, void* d_ws, size_t ws_size,
                              hipStream_t stream) {
    const float* x   = (const float*)d_in[0];
    const int* ei    = (const int*)d_in[1];
    const int* batch = (const int*)d_in[2];
    const float* W1l = (const float*)d_in[3];
    const float* b1  = (const float*)d_in[4];
    const float* W1r = (const float*)d_in[5];
    const float* W2l = (const float*)d_in[6];
    const float* b2  = (const float*)d_in[7];
    const float* W2r = (const float*)d_in[8];
    const float* Wfc = (const float*)d_in[9];
    const float* bfc = (const float*)d_in[10];
    float* out = (float*)d_out;

    const int* src = ei;
    const int* dst = ei + N_EDGES;

    // workspace layout (bytes, 256-aligned)
    const size_t SZ_FEAT = (size_t)N_NODES * DIM * sizeof(float); // 12.8 MB
    char* ws = (char*)d_ws;
    float* agg  = (float*)(ws);
    float* h1   = (float*)(ws + SZ_FEAT);
    float* h2   = (float*)(ws + 2 * SZ_FEAT);
    float* deg  = (float*)(ws + 3 * SZ_FEAT);
    float* psum = (float*)(ws + 3 * SZ_FEAT + 256 * 1024);
    float* pcnt = psum + N_GRAPHS * DIM;

    const int edgeThreads = 256;
    const int edgeBlocks = (int)(((long long)N_EDGES * DIM + edgeThreads - 1) / edgeThreads);
    const int nodeBlocks = (N_NODES + 3) / 4;  // 4 nodes per 256-thread block

    const int poolWaves = (N_NODES + POOL_NODES_PER_WAVE - 1) / POOL_NODES_PER_WAVE;
    const int poolBlocks = (poolWaves + 3) / 4; // 4 waves per 256-thread block

    // ---- Layer 1 ----
    hipMemsetAsync(agg, 0, SZ_FEAT, stream);
    hipMemsetAsync(deg, 0, (size_t)N_NODES * sizeof(float), stream);
    hipMemsetAsync(psum, 0, (size_t)(N_GRAPHS * DIM + N_GRAPHS) * sizeof(float), stream);

    scatter_kernel<<<edgeBlocks, edgeThreads, 0, stream>>>(x, src, dst, agg, deg, 1);
    sage_update_kernel<<<nodeBlocks, 256, 0, stream>>>(x, agg, deg, W1l, b1, W1r, h1, 1);

    // ---- Layer 2 ----
    hipMemsetAsync(agg, 0, SZ_FEAT, stream);
    scatter_kernel<<<edgeBlocks, edgeThreads, 0, stream>>>(h1, src, dst, agg, deg, 0);
    sage_update_kernel<<<nodeBlocks, 256, 0, stream>>>(h1, agg, deg, W2l, b2, W2r, h2, 1);

    // ---- Pool + FC ----
    pool_kernel<<<poolBlocks, 256, 0, stream>>>(h2, batch, psum, pcnt);
    fc_kernel<<<1, 512, 0, stream>>>(psum, pcnt, Wfc, bfc, out);
}

// Round 3
// 453.667 us; speedup vs baseline: 2.3601x; 1.5186x over previous
//
#include <hip/hip_runtime.h>
#include <hip/hip_bf16.h>

#define N_NODES 50000
#define N_EDGES 1000000
#define DIM 64
#define N_GRAPHS 64
#define OUT_DIM 8
#define POOL_NODES_PER_WAVE 16
#define NODES_PER_WAVE 4   // sage_layer: nodes handled per wave

// ---------------------------------------------------------------------------
// CSR build step 1: histogram of dst (in-degree counts)
// ---------------------------------------------------------------------------
__global__ void hist_kernel(const int* __restrict__ dst, int* __restrict__ cnt) {
    int e = blockIdx.x * blockDim.x + threadIdx.x;
    if (e < N_EDGES) atomicAdd(&cnt[dst[e]], 1);
}

// ---------------------------------------------------------------------------
// CSR build step 2: exclusive prefix sum over 50k counts (single block).
// ---------------------------------------------------------------------------
__global__ void scan_kernel(const int* __restrict__ cnt, int* __restrict__ row_start) {
    __shared__ int part[1024];
    int tid = threadIdx.x;
    const int CH = (N_NODES + 1023) / 1024;  // 49
    int lo = tid * CH;
    int hi = lo + CH; if (hi > N_NODES) hi = N_NODES;
    int s = 0;
    if (lo < N_NODES) for (int n = lo; n < hi; ++n) s += cnt[n];
    part[tid] = s;
    __syncthreads();
    // inclusive Hillis-Steele scan
    for (int off = 1; off < 1024; off <<= 1) {
        int v = (tid >= off) ? part[tid - off] : 0;
        __syncthreads();
        part[tid] += v;
        __syncthreads();
    }
    int base = (tid == 0) ? 0 : part[tid - 1];
    if (lo < N_NODES) {
        for (int n = lo; n < hi; ++n) { row_start[n] = base; base += cnt[n]; }
    }
    if (tid == 1023) row_start[N_NODES] = part[1023];  // == N_EDGES
}

// ---------------------------------------------------------------------------
// CSR build step 3: scatter src ids into CSR slots.
// ---------------------------------------------------------------------------
__global__ void fill_kernel(const int* __restrict__ src, const int* __restrict__ dst,
                            const int* __restrict__ row_start, int* __restrict__ cursor,
                            int* __restrict__ csr) {
    int e = blockIdx.x * blockDim.x + threadIdx.x;
    if (e >= N_EDGES) return;
    int d = dst[e];
    int pos = atomicAdd(&cursor[d], 1);
    csr[row_start[d] + pos] = src[e];
}

// ---------------------------------------------------------------------------
// Fused SAGE layer: per node (one wave, lane j = feature j):
//   mean_j = (1/max(deg,1)) * sum_{s in N(n)} feat[s][j]      (coalesced gather)
//   out[n][j] = relu( sum_k mean_k*Wl[k][j] + b[j] + x_k*Wr[k][j] )
// Cross-lane mean_k / x_k via __shfl broadcast; weights staged in LDS.
// ---------------------------------------------------------------------------
__global__ void sage_layer_kernel(const float* __restrict__ feat,
                                  const int* __restrict__ row_start,
                                  const int* __restrict__ csr,
                                  const float* __restrict__ Wl,
                                  const float* __restrict__ b,
                                  const float* __restrict__ Wr,
                                  float* __restrict__ out) {
    __shared__ float sWl[DIM * DIM];
    __shared__ float sWr[DIM * DIM];
    for (int i = threadIdx.x; i < DIM * DIM; i += blockDim.x) {
        sWl[i] = Wl[i];
        sWr[i] = Wr[i];
    }
    __syncthreads();

    int wv = blockIdx.x * (blockDim.x >> 6) + (threadIdx.x >> 6);
    int j = threadIdx.x & 63;
    float bj = b[j];

    for (int r = 0; r < NODES_PER_WAVE; ++r) {
        int n = wv * NODES_PER_WAVE + r;
        if (n >= N_NODES) break;
        int rs = row_start[n], re = row_start[n + 1];

        float acc = 0.0f;
        int i = rs;
        for (; i + 4 <= re; i += 4) {
            int s0 = csr[i], s1 = csr[i + 1], s2 = csr[i + 2], s3 = csr[i + 3];
            float a0 = feat[(long long)s0 * DIM + j];
            float a1 = feat[(long long)s1 * DIM + j];
            float a2 = feat[(long long)s2 * DIM + j];
            float a3 = feat[(long long)s3 * DIM + j];
            acc += (a0 + a1) + (a2 + a3);
        }
        for (; i < re; ++i) acc += feat[(long long)csr[i] * DIM + j];

        float mv = acc * (1.0f / fmaxf((float)(re - rs), 1.0f));
        float xv = feat[(long long)n * DIM + j];

        float sum = bj;
        #pragma unroll
        for (int k = 0; k < DIM; ++k) {
            sum += __shfl(mv, k) * sWl[k * DIM + j];
            sum += __shfl(xv, k) * sWr[k * DIM + j];
        }
        out[(long long)n * DIM + j] = fmaxf(sum, 0.0f);
    }
}

// ---------------------------------------------------------------------------
// Global mean pool — segmented register reduction (batch sorted).
// ---------------------------------------------------------------------------
__global__ void pool_kernel(const float* __restrict__ h,
                            const int* __restrict__ batch,
                            float* __restrict__ psum,
                            float* __restrict__ pcnt) {
    int wave = blockIdx.x * (blockDim.x >> 6) + (threadIdx.x >> 6);
    int j = threadIdx.x & 63;
    int start = wave * POOL_NODES_PER_WAVE;
    if (start >= N_NODES) return;
    int end = start + POOL_NODES_PER_WAVE;
    if (end > N_NODES) end = N_NODES;

    int g = batch[start];
    float acc = 0.0f;
    float cnt = 0.0f;
    for (int n = start; n < end; ++n) {
        int gn = batch[n];
        if (gn != g) {
            atomicAdd(&psum[g * DIM + j], acc);
            if (j == 0) atomicAdd(&pcnt[g], cnt);
            g = gn;
            acc = 0.0f;
            cnt = 0.0f;
        }
        acc += h[(long long)n * DIM + j];
        cnt += 1.0f;
    }
    atomicAdd(&psum[g * DIM + j], acc);
    if (j == 0) atomicAdd(&pcnt[g], cnt);
}

// ---------------------------------------------------------------------------
// Final FC: out[g][o] = (psum[g]/max(cnt,1)) @ Wfc + bfc   (64 x 8)
// ---------------------------------------------------------------------------
__global__ void fc_kernel(const float* __restrict__ psum,
                          const float* __restrict__ pcnt,
                          const float* __restrict__ Wfc,
                          const float* __restrict__ bfc,
                          float* __restrict__ out) {
    int tid = threadIdx.x;
    if (tid >= N_GRAPHS * OUT_DIM) return;
    int g = tid >> 3;
    int o = tid & 7;
    float inv = 1.0f / fmaxf(pcnt[g], 1.0f);
    float s = bfc[o];
    #pragma unroll
    for (int k = 0; k < DIM; ++k) {
        s += psum[g * DIM + k] * inv * Wfc[k * OUT_DIM + o];
    }
    out[g * OUT_DIM + o] = s;
}

extern "C" void kernel_launch(void* const* d_in, const int* in_sizes, int n_in,
                              void* d_out, int out_size, void* d_ws, size_t ws_size,
                              hipStream_t stream) {
    const float* x   = (const float*)d_in[0];
    const int* ei    = (const int*)d_in[1];
    const int* batch = (const int*)d_in[2];
    const float* W1l = (const float*)d_in[3];
    const float* b1  = (const float*)d_in[4];
    const float* W1r = (const float*)d_in[5];
    const float* W2l = (const float*)d_in[6];
    const float* b2  = (const float*)d_in[7];
    const float* W2r = (const float*)d_in[8];
    const float* Wfc = (const float*)d_in[9];
    const float* bfc = (const float*)d_in[10];
    float* out = (float*)d_out;

    const int* src = ei;
    const int* dst = ei + N_EDGES;

    // workspace layout (bytes)
    const size_t SZ_FEAT = (size_t)N_NODES * DIM * sizeof(float);  // 12.8 MB
    const size_t SZ_CSR  = (size_t)N_EDGES * sizeof(int);          // 4 MB
    const size_t SZ_CNT  = ((size_t)(N_NODES + 1) * sizeof(int) + 255) & ~(size_t)255;
    char* ws = (char*)d_ws;
    float* h1        = (float*)(ws);
    float* h2        = (float*)(ws + SZ_FEAT);
    int*   csr       = (int*)(ws + 2 * SZ_FEAT);
    int*   cnt       = (int*)(ws + 2 * SZ_FEAT + SZ_CSR);
    int*   row_start = (int*)(ws + 2 * SZ_FEAT + SZ_CSR + SZ_CNT);
    int*   cursor    = (int*)(ws + 2 * SZ_FEAT + SZ_CSR + 2 * SZ_CNT);
    float* psum      = (float*)(ws + 2 * SZ_FEAT + SZ_CSR + 3 * SZ_CNT);
    float* pcnt      = psum + N_GRAPHS * DIM;

    const int edgeBlocks = (N_EDGES + 255) / 256;
    const int layerWaves = (N_NODES + NODES_PER_WAVE - 1) / NODES_PER_WAVE;
    const int layerBlocks = (layerWaves + 3) / 4;
    const int poolWaves = (N_NODES + POOL_NODES_PER_WAVE - 1) / POOL_NODES_PER_WAVE;
    const int poolBlocks = (poolWaves + 3) / 4;

    // ---- zero accumulators ----
    hipMemsetAsync(cnt, 0, (size_t)N_NODES * sizeof(int), stream);
    hipMemsetAsync(cursor, 0, (size_t)N_NODES * sizeof(int), stream);
    hipMemsetAsync(psum, 0, (size_t)(N_GRAPHS * DIM + N_GRAPHS) * sizeof(float), stream);

    // ---- CSR build (shared by both layers) ----
    hist_kernel<<<edgeBlocks, 256, 0, stream>>>(dst, cnt);
    scan_kernel<<<1, 1024, 0, stream>>>(cnt, row_start);
    fill_kernel<<<edgeBlocks, 256, 0, stream>>>(src, dst, row_start, cursor, csr);

    // ---- Layer 1 + Layer 2 (fused gather + update + relu) ----
    sage_layer_kernel<<<layerBlocks, 256, 0, stream>>>(x, row_start, csr, W1l, b1, W1r, h1);
    sage_layer_kernel<<<layerBlocks, 256, 0, stream>>>(h1, row_start, csr, W2l, b2, W2r, h2);

    // ---- Pool + FC ----
    pool_kernel<<<poolBlocks, 256, 0, stream>>>(h2, batch, psum, pcnt);
    fc_kernel<<<1, 512, 0, stream>>>(psum, pcnt, Wfc, bfc, out);
}

// Round 4
// 332.522 us; speedup vs baseline: 3.2200x; 1.3643x over previous
//
#include <hip/hip_runtime.h>
#include <hip/hip_bf16.h>

#define N_NODES 50000
#define N_EDGES 1000000
#define DIM 64
#define N_GRAPHS 64
#define OUT_DIM 8
#define NPW 8                 // update: nodes per wave
#define NBLK_SCAN 196         // ceil(50000/256)

// ---------------------------------------------------------------------------
// CSR build 1: in-degree histogram (int4-vectorized edge reads)
// ---------------------------------------------------------------------------
__global__ void hist_kernel(const int* __restrict__ dst, int* __restrict__ cnt) {
    int e4 = blockIdx.x * blockDim.x + threadIdx.x;
    if (e4 >= N_EDGES / 4) return;
    int4 d = ((const int4*)dst)[e4];
    atomicAdd(&cnt[d.x], 1);
    atomicAdd(&cnt[d.y], 1);
    atomicAdd(&cnt[d.z], 1);
    atomicAdd(&cnt[d.w], 1);
}

// ---------------------------------------------------------------------------
// CSR build 2a: per-block (256-elem chunk) reduction of cnt -> bsum
// ---------------------------------------------------------------------------
__global__ void reduce_kernel(const int* __restrict__ cnt, int* __restrict__ bsum) {
    __shared__ int sd[256];
    int t = threadIdx.x;
    int idx = blockIdx.x * 256 + t;
    sd[t] = (idx < N_NODES) ? cnt[idx] : 0;
    __syncthreads();
    for (int off = 128; off > 0; off >>= 1) {
        if (t < off) sd[t] += sd[t + off];
        __syncthreads();
    }
    if (t == 0) bsum[blockIdx.x] = sd[0];
}

// ---------------------------------------------------------------------------
// CSR build 2b: exclusive scan of the 196 block sums (single block)
// ---------------------------------------------------------------------------
__global__ void scan_bsum_kernel(const int* __restrict__ bsum, int* __restrict__ boff,
                                 int* __restrict__ row_start) {
    __shared__ int sd[256];
    int t = threadIdx.x;
    int v = (t < NBLK_SCAN) ? bsum[t] : 0;
    sd[t] = v;
    __syncthreads();
    for (int off = 1; off < 256; off <<= 1) {
        int u = (t >= off) ? sd[t - off] : 0;
        __syncthreads();
        sd[t] += u;
        __syncthreads();
    }
    if (t < NBLK_SCAN) boff[t] = sd[t] - v;        // exclusive block offset
    if (t == 0) row_start[N_NODES] = N_EDGES;      // total is exact by construction
}

// ---------------------------------------------------------------------------
// CSR build 2c: per-block local exclusive scan + block offset -> row_start
// ---------------------------------------------------------------------------
__global__ void scan_write_kernel(const int* __restrict__ cnt, const int* __restrict__ boff,
                                  int* __restrict__ row_start) {
    __shared__ int sd[256];
    int t = threadIdx.x;
    int idx = blockIdx.x * 256 + t;
    int v = (idx < N_NODES) ? cnt[idx] : 0;
    sd[t] = v;
    __syncthreads();
    for (int off = 1; off < 256; off <<= 1) {
        int u = (t >= off) ? sd[t - off] : 0;
        __syncthreads();
        sd[t] += u;
        __syncthreads();
    }
    if (idx < N_NODES) row_start[idx] = sd[t] - v + boff[blockIdx.x];
}

// ---------------------------------------------------------------------------
// CSR build 3: scatter src ids (cursor = copy of row_start, atomic slot alloc)
// ---------------------------------------------------------------------------
__global__ void fill_kernel(const int* __restrict__ src, const int* __restrict__ dst,
                            int* __restrict__ cursor, int* __restrict__ csr) {
    int e4 = blockIdx.x * blockDim.x + threadIdx.x;
    if (e4 >= N_EDGES / 4) return;
    int4 s = ((const int4*)src)[e4];
    int4 d = ((const int4*)dst)[e4];
    csr[atomicAdd(&cursor[d.x], 1)] = s.x;
    csr[atomicAdd(&cursor[d.y], 1)] = s.y;
    csr[atomicAdd(&cursor[d.z], 1)] = s.z;
    csr[atomicAdd(&cursor[d.w], 1)] = s.w;
}

// ---------------------------------------------------------------------------
// Neighbor-mean gather: one wave per node. 4 groups x 16 lanes; group g loads
// neighbor (i+g)'s row as float4 (1 KB per wave-instr), cross-group shfl_xor
// reduce, lanes 0-15 write mean row. No LDS -> full occupancy.
// ---------------------------------------------------------------------------
__global__ void mean_kernel(const float* __restrict__ feat,
                            const int* __restrict__ row_start,
                            const int* __restrict__ csr,
                            float* __restrict__ mean) {
    int wv = (blockIdx.x * blockDim.x + threadIdx.x) >> 6;
    if (wv >= N_NODES) return;
    int lane = threadIdx.x & 63;
    int grp = lane >> 4;
    int fi = lane & 15;
    int rs = row_start[wv], re = row_start[wv + 1];

    float4 acc = make_float4(0.f, 0.f, 0.f, 0.f);
    int i = rs;
    #pragma unroll 2
    for (; i + 4 <= re; i += 4) {
        int s = csr[i + grp];
        float4 v = ((const float4*)(feat + (size_t)s * DIM))[fi];
        acc.x += v.x; acc.y += v.y; acc.z += v.z; acc.w += v.w;
    }
    if (i + grp < re) {
        int s = csr[i + grp];
        float4 v = ((const float4*)(feat + (size_t)s * DIM))[fi];
        acc.x += v.x; acc.y += v.y; acc.z += v.z; acc.w += v.w;
    }
    // reduce across the 4 groups
    acc.x += __shfl_xor(acc.x, 16); acc.y += __shfl_xor(acc.y, 16);
    acc.z += __shfl_xor(acc.z, 16); acc.w += __shfl_xor(acc.w, 16);
    acc.x += __shfl_xor(acc.x, 32); acc.y += __shfl_xor(acc.y, 32);
    acc.z += __shfl_xor(acc.z, 32); acc.w += __shfl_xor(acc.w, 32);

    if (grp == 0) {
        float inv = 1.0f / fmaxf((float)(re - rs), 1.0f);
        float4 m = make_float4(acc.x * inv, acc.y * inv, acc.z * inv, acc.w * inv);
        ((float4*)(mean + (size_t)wv * DIM))[fi] = m;
    }
}

// ---------------------------------------------------------------------------
// Node update: lane j holds weight COLUMNS j of Wl,Wr in VGPRs (128 regs);
// node index forced wave-uniform (readfirstlane) so mean/x element reads are
// scalar broadcasts. out[n][j] = relu(sum_k m[k]*Wl[k][j] + x[k]*Wr[k][j] + b[j]).
// do_pool: instead of writing rows, segment-accumulate into psum/pcnt
// (batch is sorted) -> h2 buffer and pool kernel eliminated.
// ---------------------------------------------------------------------------
__global__ void update_kernel(const float* __restrict__ mean,
                              const float* __restrict__ x,
                              const float* __restrict__ Wl,
                              const float* __restrict__ b,
                              const float* __restrict__ Wr,
                              float* __restrict__ outNodes,
                              const int* __restrict__ batch,
                              float* __restrict__ psum,
                              float* __restrict__ pcnt,
                              int do_pool) {
    int j = threadIdx.x & 63;
    int wv = (blockIdx.x * blockDim.x + threadIdx.x) >> 6;
    int n0 = wv * NPW;
    if (n0 >= N_NODES) return;

    float wl[DIM], wr[DIM];
    #pragma unroll
    for (int k = 0; k < DIM; ++k) {
        wl[k] = Wl[k * DIM + j];
        wr[k] = Wr[k * DIM + j];
    }
    float bj = b[j];

    float pacc = 0.0f, pcc = 0.0f;
    int pg = do_pool ? batch[n0] : 0;

    for (int r = 0; r < NPW; ++r) {
        int n = n0 + r;
        if (n >= N_NODES) break;
        int un = __builtin_amdgcn_readfirstlane(n);
        const float* mrow = mean + (size_t)un * DIM;
        const float* xrow = x + (size_t)un * DIM;
        float sum = bj;
        #pragma unroll
        for (int k = 0; k < DIM; ++k) {
            sum = fmaf(mrow[k], wl[k], sum);
            sum = fmaf(xrow[k], wr[k], sum);
        }
        sum = fmaxf(sum, 0.0f);
        if (do_pool) {
            int g = batch[un];
            if (g != pg) {
                atomicAdd(&psum[pg * DIM + j], pacc);
                if (j == 0) atomicAdd(&pcnt[pg], pcc);
                pg = g; pacc = 0.0f; pcc = 0.0f;
            }
            pacc += sum;
            pcc += 1.0f;
        } else {
            outNodes[(size_t)un * DIM + j] = sum;
        }
    }
    if (do_pool) {
        atomicAdd(&psum[pg * DIM + j], pacc);
        if (j == 0) atomicAdd(&pcnt[pg], pcc);
    }
}

// ---------------------------------------------------------------------------
// Final FC: out[g][o] = (psum[g]/max(cnt,1)) @ Wfc + bfc   (64 x 8)
// ---------------------------------------------------------------------------
__global__ void fc_kernel(const float* __restrict__ psum,
                          const float* __restrict__ pcnt,
                          const float* __restrict__ Wfc,
                          const float* __restrict__ bfc,
                          float* __restrict__ out) {
    int tid = threadIdx.x;
    if (tid >= N_GRAPHS * OUT_DIM) return;
    int g = tid >> 3;
    int o = tid & 7;
    float inv = 1.0f / fmaxf(pcnt[g], 1.0f);
    float s = bfc[o];
    #pragma unroll
    for (int k = 0; k < DIM; ++k) {
        s += psum[g * DIM + k] * inv * Wfc[k * OUT_DIM + o];
    }
    out[g * OUT_DIM + o] = s;
}

extern "C" void kernel_launch(void* const* d_in, const int* in_sizes, int n_in,
                              void* d_out, int out_size, void* d_ws, size_t ws_size,
                              hipStream_t stream) {
    const float* x   = (const float*)d_in[0];
    const int* ei    = (const int*)d_in[1];
    const int* batch = (const int*)d_in[2];
    const float* W1l = (const float*)d_in[3];
    const float* b1  = (const float*)d_in[4];
    const float* W1r = (const float*)d_in[5];
    const float* W2l = (const float*)d_in[6];
    const float* b2  = (const float*)d_in[7];
    const float* W2r = (const float*)d_in[8];
    const float* Wfc = (const float*)d_in[9];
    const float* bfc = (const float*)d_in[10];
    float* out = (float*)d_out;

    const int* src = ei;
    const int* dst = ei + N_EDGES;

    // workspace layout (~30.4 MB)
    const size_t SZ_FEAT = (size_t)N_NODES * DIM * sizeof(float);  // 12.8 MB
    const size_t SZ_CSR  = (size_t)N_EDGES * sizeof(int);          // 4 MB
    const size_t SZ_CNT  = ((size_t)(N_NODES + 1) * sizeof(int) + 255) & ~(size_t)255;
    char* ws = (char*)d_ws;
    float* meanb     = (float*)(ws);
    float* h1        = (float*)(ws + SZ_FEAT);
    int*   csr       = (int*)(ws + 2 * SZ_FEAT);
    int*   cnt       = (int*)(ws + 2 * SZ_FEAT + SZ_CSR);
    int*   row_start = (int*)(ws + 2 * SZ_FEAT + SZ_CSR + SZ_CNT);
    int*   cursor    = (int*)(ws + 2 * SZ_FEAT + SZ_CSR + 2 * SZ_CNT);
    int*   bsum      = (int*)(ws + 2 * SZ_FEAT + SZ_CSR + 3 * SZ_CNT);
    int*   boff      = bsum + 256;
    float* psum      = (float*)(bsum + 512);
    float* pcnt      = psum + N_GRAPHS * DIM;

    const int edge4Blocks = (N_EDGES / 4 + 255) / 256;               // 977
    const int meanBlocks  = (N_NODES + 3) / 4;                       // 12500 (4 waves/blk)
    const int updWaves    = (N_NODES + NPW - 1) / NPW;               // 6250
    const int updBlocks   = (updWaves + 3) / 4;                      // 1563

    hipMemsetAsync(cnt, 0, (size_t)N_NODES * sizeof(int), stream);
    hipMemsetAsync(psum, 0, (size_t)(N_GRAPHS * DIM + N_GRAPHS) * sizeof(float), stream);

    // ---- CSR build ----
    hist_kernel<<<edge4Blocks, 256, 0, stream>>>(dst, cnt);
    reduce_kernel<<<NBLK_SCAN, 256, 0, stream>>>(cnt, bsum);
    scan_bsum_kernel<<<1, 256, 0, stream>>>(bsum, boff, row_start);
    scan_write_kernel<<<NBLK_SCAN, 256, 0, stream>>>(cnt, boff, row_start);
    hipMemcpyAsync(cursor, row_start, (size_t)N_NODES * sizeof(int),
                   hipMemcpyDeviceToDevice, stream);
    fill_kernel<<<edge4Blocks, 256, 0, stream>>>(src, dst, cursor, csr);

    // ---- Layer 1 ----
    mean_kernel<<<meanBlocks, 256, 0, stream>>>(x, row_start, csr, meanb);
    update_kernel<<<updBlocks, 256, 0, stream>>>(meanb, x, W1l, b1, W1r, h1,
                                                 nullptr, nullptr, nullptr, 0);
    // ---- Layer 2 (pool fused) ----
    mean_kernel<<<meanBlocks, 256, 0, stream>>>(h1, row_start, csr, meanb);
    update_kernel<<<updBlocks, 256, 0, stream>>>(meanb, h1, W2l, b2, W2r, nullptr,
                                                 batch, psum, pcnt, 1);
    // ---- FC ----
    fc_kernel<<<1, 512, 0, stream>>>(psum, pcnt, Wfc, bfc, out);
}

// Round 5
// 298.589 us; speedup vs baseline: 3.5859x; 1.1136x over previous
//
#include <hip/hip_runtime.h>
#include <hip/hip_bf16.h>

#define N_NODES 50000
#define N_EDGES 1000000
#define DIM 64
#define N_GRAPHS 64
#define OUT_DIM 8
#define NPW 16                // update: nodes per wave
#define NBLK_SCAN 196         // ceil(50000/256)

// ---------------------------------------------------------------------------
// CSR build 1: in-degree histogram (int4-vectorized edge reads)
// ---------------------------------------------------------------------------
__global__ void hist_kernel(const int* __restrict__ dst, int* __restrict__ cnt) {
    int e4 = blockIdx.x * blockDim.x + threadIdx.x;
    if (e4 >= N_EDGES / 4) return;
    int4 d = ((const int4*)dst)[e4];
    atomicAdd(&cnt[d.x], 1);
    atomicAdd(&cnt[d.y], 1);
    atomicAdd(&cnt[d.z], 1);
    atomicAdd(&cnt[d.w], 1);
}

// ---------------------------------------------------------------------------
// CSR build 2a: per-block (256-elem chunk) reduction of cnt -> bsum
// ---------------------------------------------------------------------------
__global__ void reduce_kernel(const int* __restrict__ cnt, int* __restrict__ bsum) {
    __shared__ int sd[256];
    int t = threadIdx.x;
    int idx = blockIdx.x * 256 + t;
    sd[t] = (idx < N_NODES) ? cnt[idx] : 0;
    __syncthreads();
    for (int off = 128; off > 0; off >>= 1) {
        if (t < off) sd[t] += sd[t + off];
        __syncthreads();
    }
    if (t == 0) bsum[blockIdx.x] = sd[0];
}

// ---------------------------------------------------------------------------
// CSR build 2b: exclusive scan of the 196 block sums (single block)
// ---------------------------------------------------------------------------
__global__ void scan_bsum_kernel(const int* __restrict__ bsum, int* __restrict__ boff,
                                 int* __restrict__ row_start) {
    __shared__ int sd[256];
    int t = threadIdx.x;
    int v = (t < NBLK_SCAN) ? bsum[t] : 0;
    sd[t] = v;
    __syncthreads();
    for (int off = 1; off < 256; off <<= 1) {
        int u = (t >= off) ? sd[t - off] : 0;
        __syncthreads();
        sd[t] += u;
        __syncthreads();
    }
    if (t < NBLK_SCAN) boff[t] = sd[t] - v;        // exclusive block offset
    if (t == 0) row_start[N_NODES] = N_EDGES;
}

// ---------------------------------------------------------------------------
// CSR build 2c: per-block local exclusive scan + block offset -> row_start
// (also emits cursor = copy of row_start, so fill needs no separate memcpy)
// ---------------------------------------------------------------------------
__global__ void scan_write_kernel(const int* __restrict__ cnt, const int* __restrict__ boff,
                                  int* __restrict__ row_start, int* __restrict__ cursor) {
    __shared__ int sd[256];
    int t = threadIdx.x;
    int idx = blockIdx.x * 256 + t;
    int v = (idx < N_NODES) ? cnt[idx] : 0;
    sd[t] = v;
    __syncthreads();
    for (int off = 1; off < 256; off <<= 1) {
        int u = (t >= off) ? sd[t - off] : 0;
        __syncthreads();
        sd[t] += u;
        __syncthreads();
    }
    if (idx < N_NODES) {
        int rs = sd[t] - v + boff[blockIdx.x];
        row_start[idx] = rs;
        cursor[idx] = rs;
    }
}

// ---------------------------------------------------------------------------
// CSR build 3: scatter src ids (cursor pre-filled with row_start)
// ---------------------------------------------------------------------------
__global__ void fill_kernel(const int* __restrict__ src, const int* __restrict__ dst,
                            int* __restrict__ cursor, int* __restrict__ csr) {
    int e4 = blockIdx.x * blockDim.x + threadIdx.x;
    if (e4 >= N_EDGES / 4) return;
    int4 s = ((const int4*)src)[e4];
    int4 d = ((const int4*)dst)[e4];
    csr[atomicAdd(&cursor[d.x], 1)] = s.x;
    csr[atomicAdd(&cursor[d.y], 1)] = s.y;
    csr[atomicAdd(&cursor[d.z], 1)] = s.z;
    csr[atomicAdd(&cursor[d.w], 1)] = s.w;
}

// ---------------------------------------------------------------------------
// Neighbor-mean gather: one wave per node. 4 groups x 16 lanes; group g loads
// neighbor rows as float4 (1 KB per wave-instr). Dual accumulators keep 8
// neighbor-row loads in flight per iteration. No LDS -> full occupancy.
// ---------------------------------------------------------------------------
__global__ __launch_bounds__(256) void mean_kernel(const float* __restrict__ feat,
                            const int* __restrict__ row_start,
                            const int* __restrict__ csr,
                            float* __restrict__ mean) {
    int wv = (blockIdx.x * blockDim.x + threadIdx.x) >> 6;
    if (wv >= N_NODES) return;
    int lane = threadIdx.x & 63;
    int grp = lane >> 4;
    int fi = lane & 15;
    int rs = row_start[wv], re = row_start[wv + 1];

    float4 a0 = make_float4(0.f, 0.f, 0.f, 0.f);
    float4 a1 = make_float4(0.f, 0.f, 0.f, 0.f);
    int i = rs;
    for (; i + 8 <= re; i += 8) {
        int s0 = csr[i + grp];
        int s1 = csr[i + 4 + grp];
        float4 v0 = ((const float4*)(feat + (size_t)s0 * DIM))[fi];
        float4 v1 = ((const float4*)(feat + (size_t)s1 * DIM))[fi];
        a0.x += v0.x; a0.y += v0.y; a0.z += v0.z; a0.w += v0.w;
        a1.x += v1.x; a1.y += v1.y; a1.z += v1.z; a1.w += v1.w;
    }
    if (i + 4 <= re) {
        int s = csr[i + grp];
        float4 v = ((const float4*)(feat + (size_t)s * DIM))[fi];
        a0.x += v.x; a0.y += v.y; a0.z += v.z; a0.w += v.w;
        i += 4;
    }
    if (i + grp < re) {
        int s = csr[i + grp];
        float4 v = ((const float4*)(feat + (size_t)s * DIM))[fi];
        a1.x += v.x; a1.y += v.y; a1.z += v.z; a1.w += v.w;
    }
    float4 acc = make_float4(a0.x + a1.x, a0.y + a1.y, a0.z + a1.z, a0.w + a1.w);

    acc.x += __shfl_xor(acc.x, 16); acc.y += __shfl_xor(acc.y, 16);
    acc.z += __shfl_xor(acc.z, 16); acc.w += __shfl_xor(acc.w, 16);
    acc.x += __shfl_xor(acc.x, 32); acc.y += __shfl_xor(acc.y, 32);
    acc.z += __shfl_xor(acc.z, 32); acc.w += __shfl_xor(acc.w, 32);

    if (grp == 0) {
        float inv = 1.0f / fmaxf((float)(re - rs), 1.0f);
        float4 m = make_float4(acc.x * inv, acc.y * inv, acc.z * inv, acc.w * inv);
        ((float4*)(mean + (size_t)wv * DIM))[fi] = m;
    }
}

// ---------------------------------------------------------------------------
// Node update: lane j holds weight COLUMNS j of Wl,Wr in VGPRs (128 regs —
// __launch_bounds__(256,2) raises the VGPR cap to 256 so they actually stay
// resident; R4's default heuristic capped at 64 and re-loaded weights).
// Node index wave-uniform (readfirstlane) -> mean/x reads are s_load
// broadcasts. do_pool: segment-accumulate into psum/pcnt (batch sorted).
// ---------------------------------------------------------------------------
__global__ __launch_bounds__(256, 2) void update_kernel(
                              const float* __restrict__ mean,
                              const float* __restrict__ x,
                              const float* __restrict__ Wl,
                              const float* __restrict__ b,
                              const float* __restrict__ Wr,
                              float* __restrict__ outNodes,
                              const int* __restrict__ batch,
                              float* __restrict__ psum,
                              float* __restrict__ pcnt,
                              int do_pool) {
    int j = threadIdx.x & 63;
    int wv = (blockIdx.x * blockDim.x + threadIdx.x) >> 6;
    int n0 = wv * NPW;
    if (n0 >= N_NODES) return;

    float wl[DIM], wr[DIM];
    #pragma unroll
    for (int k = 0; k < DIM; ++k) wl[k] = Wl[k * DIM + j];
    #pragma unroll
    for (int k = 0; k < DIM; ++k) wr[k] = Wr[k * DIM + j];
    float bj = b[j];

    float pacc = 0.0f, pcc = 0.0f;
    int pg = do_pool ? batch[n0] : 0;

    #pragma unroll 2
    for (int r = 0; r < NPW; ++r) {
        int n = n0 + r;
        if (n >= N_NODES) break;
        int un = __builtin_amdgcn_readfirstlane(n);
        const float* mrow = mean + (size_t)un * DIM;
        const float* xrow = x + (size_t)un * DIM;
        float sum = bj;
        #pragma unroll
        for (int k = 0; k < DIM; ++k) {
            sum = fmaf(mrow[k], wl[k], sum);
            sum = fmaf(xrow[k], wr[k], sum);
        }
        sum = fmaxf(sum, 0.0f);
        if (do_pool) {
            int g = batch[un];
            if (g != pg) {
                atomicAdd(&psum[pg * DIM + j], pacc);
                if (j == 0) atomicAdd(&pcnt[pg], pcc);
                pg = g; pacc = 0.0f; pcc = 0.0f;
            }
            pacc += sum;
            pcc += 1.0f;
        } else {
            outNodes[(size_t)un * DIM + j] = sum;
        }
    }
    if (do_pool) {
        atomicAdd(&psum[pg * DIM + j], pacc);
        if (j == 0) atomicAdd(&pcnt[pg], pcc);
    }
}

// ---------------------------------------------------------------------------
// Final FC: out[g][o] = (psum[g]/max(cnt,1)) @ Wfc + bfc   (64 x 8)
// ---------------------------------------------------------------------------
__global__ void fc_kernel(const float* __restrict__ psum,
                          const float* __restrict__ pcnt,
                          const float* __restrict__ Wfc,
                          const float* __restrict__ bfc,
                          float* __restrict__ out) {
    int tid = threadIdx.x;
    if (tid >= N_GRAPHS * OUT_DIM) return;
    int g = tid >> 3;
    int o = tid & 7;
    float inv = 1.0f / fmaxf(pcnt[g], 1.0f);
    float s = bfc[o];
    #pragma unroll
    for (int k = 0; k < DIM; ++k) {
        s += psum[g * DIM + k] * inv * Wfc[k * OUT_DIM + o];
    }
    out[g * OUT_DIM + o] = s;
}

extern "C" void kernel_launch(void* const* d_in, const int* in_sizes, int n_in,
                              void* d_out, int out_size, void* d_ws, size_t ws_size,
                              hipStream_t stream) {
    const float* x   = (const float*)d_in[0];
    const int* ei    = (const int*)d_in[1];
    const int* batch = (const int*)d_in[2];
    const float* W1l = (const float*)d_in[3];
    const float* b1  = (const float*)d_in[4];
    const float* W1r = (const float*)d_in[5];
    const float* W2l = (const float*)d_in[6];
    const float* b2  = (const float*)d_in[7];
    const float* W2r = (const float*)d_in[8];
    const float* Wfc = (const float*)d_in[9];
    const float* bfc = (const float*)d_in[10];
    float* out = (float*)d_out;

    const int* src = ei;
    const int* dst = ei + N_EDGES;

    // workspace layout (~30.4 MB)
    const size_t SZ_FEAT = (size_t)N_NODES * DIM * sizeof(float);  // 12.8 MB
    const size_t SZ_CSR  = (size_t)N_EDGES * sizeof(int);          // 4 MB
    const size_t SZ_CNT  = ((size_t)(N_NODES + 1) * sizeof(int) + 255) & ~(size_t)255;
    char* ws = (char*)d_ws;
    float* meanb     = (float*)(ws);
    float* h1        = (float*)(ws + SZ_FEAT);
    int*   csr       = (int*)(ws + 2 * SZ_FEAT);
    int*   cnt       = (int*)(ws + 2 * SZ_FEAT + SZ_CSR);
    int*   row_start = (int*)(ws + 2 * SZ_FEAT + SZ_CSR + SZ_CNT);
    int*   cursor    = (int*)(ws + 2 * SZ_FEAT + SZ_CSR + 2 * SZ_CNT);
    int*   bsum      = (int*)(ws + 2 * SZ_FEAT + SZ_CSR + 3 * SZ_CNT);
    int*   boff      = bsum + 256;
    float* psum      = (float*)(bsum + 512);
    float* pcnt      = psum + N_GRAPHS * DIM;

    const int edge4Blocks = (N_EDGES / 4 + 255) / 256;               // 977
    const int meanBlocks  = (N_NODES + 3) / 4;                       // 12500 (4 waves/blk)
    const int updWaves    = (N_NODES + NPW - 1) / NPW;               // 3125
    const int updBlocks   = (updWaves + 3) / 4;                      // 782

    hipMemsetAsync(cnt, 0, (size_t)N_NODES * sizeof(int), stream);
    hipMemsetAsync(psum, 0, (size_t)(N_GRAPHS * DIM + N_GRAPHS) * sizeof(float), stream);

    // ---- CSR build ----
    hist_kernel<<<edge4Blocks, 256, 0, stream>>>(dst, cnt);
    reduce_kernel<<<NBLK_SCAN, 256, 0, stream>>>(cnt, bsum);
    scan_bsum_kernel<<<1, 256, 0, stream>>>(bsum, boff, row_start);
    scan_write_kernel<<<NBLK_SCAN, 256, 0, stream>>>(cnt, boff, row_start, cursor);
    fill_kernel<<<edge4Blocks, 256, 0, stream>>>(src, dst, cursor, csr);

    // ---- Layer 1 ----
    mean_kernel<<<meanBlocks, 256, 0, stream>>>(x, row_start, csr, meanb);
    update_kernel<<<updBlocks, 256, 0, stream>>>(meanb, x, W1l, b1, W1r, h1,
                                                 nullptr, nullptr, nullptr, 0);
    // ---- Layer 2 (pool fused) ----
    mean_kernel<<<meanBlocks, 256, 0, stream>>>(h1, row_start, csr, meanb);
    update_kernel<<<updBlocks, 256, 0, stream>>>(meanb, h1, W2l, b2, W2r, nullptr,
                                                 batch, psum, pcnt, 1);
    // ---- FC ----
    fc_kernel<<<1, 512, 0, stream>>>(psum, pcnt, Wfc, bfc, out);
}

// Round 6
// 280.867 us; speedup vs baseline: 3.8122x; 1.0631x over previous
//
#include <hip/hip_runtime.h>
#include <hip/hip_bf16.h>

#define N_NODES 50000
#define N_EDGES 1000000
#define DIM 64
#define N_GRAPHS 64
#define OUT_DIM 8
#define NPW 16                // update: nodes per wave
#define NBLK_SCAN 196         // ceil(50000/256)
#define NPART 8               // fill: one dst-range partition per XCD
#define PARTBLK 128           // blocks per partition

// ---------------------------------------------------------------------------
// CSR build 1: in-degree histogram (int4-vectorized edge reads)
// ---------------------------------------------------------------------------
__global__ void hist_kernel(const int* __restrict__ dst, int* __restrict__ cnt) {
    int e4 = blockIdx.x * blockDim.x + threadIdx.x;
    if (e4 >= N_EDGES / 4) return;
    int4 d = ((const int4*)dst)[e4];
    atomicAdd(&cnt[d.x], 1);
    atomicAdd(&cnt[d.y], 1);
    atomicAdd(&cnt[d.z], 1);
    atomicAdd(&cnt[d.w], 1);
}

// ---------------------------------------------------------------------------
// CSR build 2a: per-block (256-elem chunk) reduction of cnt -> bsum
// ---------------------------------------------------------------------------
__global__ void reduce_kernel(const int* __restrict__ cnt, int* __restrict__ bsum) {
    __shared__ int sd[256];
    int t = threadIdx.x;
    int idx = blockIdx.x * 256 + t;
    sd[t] = (idx < N_NODES) ? cnt[idx] : 0;
    __syncthreads();
    for (int off = 128; off > 0; off >>= 1) {
        if (t < off) sd[t] += sd[t + off];
        __syncthreads();
    }
    if (t == 0) bsum[blockIdx.x] = sd[0];
}

// ---------------------------------------------------------------------------
// CSR build 2b: exclusive scan of the 196 block sums (single block)
// ---------------------------------------------------------------------------
__global__ void scan_bsum_kernel(const int* __restrict__ bsum, int* __restrict__ boff,
                                 int* __restrict__ row_start) {
    __shared__ int sd[256];
    int t = threadIdx.x;
    int v = (t < NBLK_SCAN) ? bsum[t] : 0;
    sd[t] = v;
    __syncthreads();
    for (int off = 1; off < 256; off <<= 1) {
        int u = (t >= off) ? sd[t - off] : 0;
        __syncthreads();
        sd[t] += u;
        __syncthreads();
    }
    if (t < NBLK_SCAN) boff[t] = sd[t] - v;        // exclusive block offset
    if (t == 0) row_start[N_NODES] = N_EDGES;
}

// ---------------------------------------------------------------------------
// CSR build 2c: per-block local exclusive scan + block offset -> row_start
// (also emits cursor = copy of row_start, so fill needs no separate memcpy)
// ---------------------------------------------------------------------------
__global__ void scan_write_kernel(const int* __restrict__ cnt, const int* __restrict__ boff,
                                  int* __restrict__ row_start, int* __restrict__ cursor) {
    __shared__ int sd[256];
    int t = threadIdx.x;
    int idx = blockIdx.x * 256 + t;
    int v = (idx < N_NODES) ? cnt[idx] : 0;
    sd[t] = v;
    __syncthreads();
    for (int off = 1; off < 256; off <<= 1) {
        int u = (t >= off) ? sd[t - off] : 0;
        __syncthreads();
        sd[t] += u;
        __syncthreads();
    }
    if (idx < N_NODES) {
        int rs = sd[t] - v + boff[blockIdx.x];
        row_start[idx] = rs;
        cursor[idx] = rs;
    }
}

// ---------------------------------------------------------------------------
// CSR build 3: XCD-partitioned scatter of src ids.
// Node range [p*6250,(p+1)*6250) -> contiguous csr byte range, owned by
// partition p = blockIdx.x & 7 (default round-robin block->XCD mapping).
// Each csr line is then written by ONE XCD: no cross-XCD dirty-line
// ping-pong (R5 showed 69 MB HBM writes for a 4 MB buffer). Every edge is
// scanned by all 8 partitions, claimed by exactly one.
// ---------------------------------------------------------------------------
__global__ void fill_part_kernel(const int* __restrict__ src, const int* __restrict__ dst,
                                 int* __restrict__ cursor, int* __restrict__ csr) {
    int part = blockIdx.x & (NPART - 1);
    int q = blockIdx.x >> 3;                 // index within partition
    int lo = part * (N_NODES / NPART);
    int hi = lo + (N_NODES / NPART);
    for (int e4 = q * blockDim.x + threadIdx.x; e4 < N_EDGES / 4;
         e4 += PARTBLK * blockDim.x) {
        int4 d = ((const int4*)dst)[e4];
        int4 s = ((const int4*)src)[e4];
        if (d.x >= lo && d.x < hi) csr[atomicAdd(&cursor[d.x], 1)] = s.x;
        if (d.y >= lo && d.y < hi) csr[atomicAdd(&cursor[d.y], 1)] = s.y;
        if (d.z >= lo && d.z < hi) csr[atomicAdd(&cursor[d.z], 1)] = s.z;
        if (d.w >= lo && d.w < hi) csr[atomicAdd(&cursor[d.w], 1)] = s.w;
    }
}

// ---------------------------------------------------------------------------
// Neighbor-mean gather: one wave per node. 4 groups x 16 lanes; group g loads
// neighbor rows as float4 (1 KB per wave-instr). Dual accumulators keep 8
// neighbor-row loads in flight per iteration. No LDS -> full occupancy.
// ---------------------------------------------------------------------------
__global__ __launch_bounds__(256) void mean_kernel(const float* __restrict__ feat,
                            const int* __restrict__ row_start,
                            const int* __restrict__ csr,
                            float* __restrict__ mean) {
    int wv = (blockIdx.x * blockDim.x + threadIdx.x) >> 6;
    if (wv >= N_NODES) return;
    int lane = threadIdx.x & 63;
    int grp = lane >> 4;
    int fi = lane & 15;
    int rs = row_start[wv], re = row_start[wv + 1];

    float4 a0 = make_float4(0.f, 0.f, 0.f, 0.f);
    float4 a1 = make_float4(0.f, 0.f, 0.f, 0.f);
    int i = rs;
    for (; i + 8 <= re; i += 8) {
        int s0 = csr[i + grp];
        int s1 = csr[i + 4 + grp];
        float4 v0 = ((const float4*)(feat + (size_t)s0 * DIM))[fi];
        float4 v1 = ((const float4*)(feat + (size_t)s1 * DIM))[fi];
        a0.x += v0.x; a0.y += v0.y; a0.z += v0.z; a0.w += v0.w;
        a1.x += v1.x; a1.y += v1.y; a1.z += v1.z; a1.w += v1.w;
    }
    if (i + 4 <= re) {
        int s = csr[i + grp];
        float4 v = ((const float4*)(feat + (size_t)s * DIM))[fi];
        a0.x += v.x; a0.y += v.y; a0.z += v.z; a0.w += v.w;
        i += 4;
    }
    if (i + grp < re) {
        int s = csr[i + grp];
        float4 v = ((const float4*)(feat + (size_t)s * DIM))[fi];
        a1.x += v.x; a1.y += v.y; a1.z += v.z; a1.w += v.w;
    }
    float4 acc = make_float4(a0.x + a1.x, a0.y + a1.y, a0.z + a1.z, a0.w + a1.w);

    acc.x += __shfl_xor(acc.x, 16); acc.y += __shfl_xor(acc.y, 16);
    acc.z += __shfl_xor(acc.z, 16); acc.w += __shfl_xor(acc.w, 16);
    acc.x += __shfl_xor(acc.x, 32); acc.y += __shfl_xor(acc.y, 32);
    acc.z += __shfl_xor(acc.z, 32); acc.w += __shfl_xor(acc.w, 32);

    if (grp == 0) {
        float inv = 1.0f / fmaxf((float)(re - rs), 1.0f);
        float4 m = make_float4(acc.x * inv, acc.y * inv, acc.z * inv, acc.w * inv);
        ((float4*)(mean + (size_t)wv * DIM))[fi] = m;
    }
}

// ---------------------------------------------------------------------------
// Node update: lane j holds weight COLUMNS j of Wl,Wr in VGPRs (128 regs;
// __launch_bounds__(256,2) raises the VGPR cap so they stay resident).
// Node index wave-uniform (readfirstlane) -> mean/x reads are scalar
// broadcasts. do_pool: segment-accumulate into psum/pcnt (batch sorted).
// ---------------------------------------------------------------------------
__global__ __launch_bounds__(256, 2) void update_kernel(
                              const float* __restrict__ mean,
                              const float* __restrict__ x,
                              const float* __restrict__ Wl,
                              const float* __restrict__ b,
                              const float* __restrict__ Wr,
                              float* __restrict__ outNodes,
                              const int* __restrict__ batch,
                              float* __restrict__ psum,
                              float* __restrict__ pcnt,
                              int do_pool) {
    int j = threadIdx.x & 63;
    int wv = (blockIdx.x * blockDim.x + threadIdx.x) >> 6;
    int n0 = wv * NPW;
    if (n0 >= N_NODES) return;

    float wl[DIM], wr[DIM];
    #pragma unroll
    for (int k = 0; k < DIM; ++k) wl[k] = Wl[k * DIM + j];
    #pragma unroll
    for (int k = 0; k < DIM; ++k) wr[k] = Wr[k * DIM + j];
    float bj = b[j];

    float pacc = 0.0f, pcc = 0.0f;
    int pg = do_pool ? batch[n0] : 0;

    #pragma unroll 2
    for (int r = 0; r < NPW; ++r) {
        int n = n0 + r;
        if (n >= N_NODES) break;
        int un = __builtin_amdgcn_readfirstlane(n);
        const float* mrow = mean + (size_t)un * DIM;
        const float* xrow = x + (size_t)un * DIM;
        float sum = bj;
        #pragma unroll
        for (int k = 0; k < DIM; ++k) {
            sum = fmaf(mrow[k], wl[k], sum);
            sum = fmaf(xrow[k], wr[k], sum);
        }
        sum = fmaxf(sum, 0.0f);
        if (do_pool) {
            int g = batch[un];
            if (g != pg) {
                atomicAdd(&psum[pg * DIM + j], pacc);
                if (j == 0) atomicAdd(&pcnt[pg], pcc);
                pg = g; pacc = 0.0f; pcc = 0.0f;
            }
            pacc += sum;
            pcc += 1.0f;
        } else {
            outNodes[(size_t)un * DIM + j] = sum;
        }
    }
    if (do_pool) {
        atomicAdd(&psum[pg * DIM + j], pacc);
        if (j == 0) atomicAdd(&pcnt[pg], pcc);
    }
}

// ---------------------------------------------------------------------------
// Final FC: out[g][o] = (psum[g]/max(cnt,1)) @ Wfc + bfc   (64 x 8)
// ---------------------------------------------------------------------------
__global__ void fc_kernel(const float* __restrict__ psum,
                          const float* __restrict__ pcnt,
                          const float* __restrict__ Wfc,
                          const float* __restrict__ bfc,
                          float* __restrict__ out) {
    int tid = threadIdx.x;
    if (tid >= N_GRAPHS * OUT_DIM) return;
    int g = tid >> 3;
    int o = tid & 7;
    float inv = 1.0f / fmaxf(pcnt[g], 1.0f);
    float s = bfc[o];
    #pragma unroll
    for (int k = 0; k < DIM; ++k) {
        s += psum[g * DIM + k] * inv * Wfc[k * OUT_DIM + o];
    }
    out[g * OUT_DIM + o] = s;
}

extern "C" void kernel_launch(void* const* d_in, const int* in_sizes, int n_in,
                              void* d_out, int out_size, void* d_ws, size_t ws_size,
                              hipStream_t stream) {
    const float* x   = (const float*)d_in[0];
    const int* ei    = (const int*)d_in[1];
    const int* batch = (const int*)d_in[2];
    const float* W1l = (const float*)d_in[3];
    const float* b1  = (const float*)d_in[4];
    const float* W1r = (const float*)d_in[5];
    const float* W2l = (const float*)d_in[6];
    const float* b2  = (const float*)d_in[7];
    const float* W2r = (const float*)d_in[8];
    const float* Wfc = (const float*)d_in[9];
    const float* bfc = (const float*)d_in[10];
    float* out = (float*)d_out;

    const int* src = ei;
    const int* dst = ei + N_EDGES;

    // workspace layout (~30.4 MB)
    const size_t SZ_FEAT = (size_t)N_NODES * DIM * sizeof(float);  // 12.8 MB
    const size_t SZ_CSR  = (size_t)N_EDGES * sizeof(int);          // 4 MB
    const size_t SZ_CNT  = ((size_t)(N_NODES + 1) * sizeof(int) + 255) & ~(size_t)255;
    char* ws = (char*)d_ws;
    float* meanb     = (float*)(ws);
    float* h1        = (float*)(ws + SZ_FEAT);
    int*   csr       = (int*)(ws + 2 * SZ_FEAT);
    int*   cnt       = (int*)(ws + 2 * SZ_FEAT + SZ_CSR);
    int*   row_start = (int*)(ws + 2 * SZ_FEAT + SZ_CSR + SZ_CNT);
    int*   cursor    = (int*)(ws + 2 * SZ_FEAT + SZ_CSR + 2 * SZ_CNT);
    int*   bsum      = (int*)(ws + 2 * SZ_FEAT + SZ_CSR + 3 * SZ_CNT);
    int*   boff      = bsum + 256;
    float* psum      = (float*)(bsum + 512);
    float* pcnt      = psum + N_GRAPHS * DIM;

    const int edge4Blocks = (N_EDGES / 4 + 255) / 256;               // 977
    const int meanBlocks  = (N_NODES + 3) / 4;                       // 12500 (4 waves/blk)
    const int updWaves    = (N_NODES + NPW - 1) / NPW;               // 3125
    const int updBlocks   = (updWaves + 3) / 4;                      // 782

    hipMemsetAsync(cnt, 0, (size_t)N_NODES * sizeof(int), stream);
    hipMemsetAsync(psum, 0, (size_t)(N_GRAPHS * DIM + N_GRAPHS) * sizeof(float), stream);

    // ---- CSR build ----
    hist_kernel<<<edge4Blocks, 256, 0, stream>>>(dst, cnt);
    reduce_kernel<<<NBLK_SCAN, 256, 0, stream>>>(cnt, bsum);
    scan_bsum_kernel<<<1, 256, 0, stream>>>(bsum, boff, row_start);
    scan_write_kernel<<<NBLK_SCAN, 256, 0, stream>>>(cnt, boff, row_start, cursor);
    fill_part_kernel<<<NPART * PARTBLK, 256, 0, stream>>>(src, dst, cursor, csr);

    // ---- Layer 1 ----
    mean_kernel<<<meanBlocks, 256, 0, stream>>>(x, row_start, csr, meanb);
    update_kernel<<<updBlocks, 256, 0, stream>>>(meanb, x, W1l, b1, W1r, h1,
                                                 nullptr, nullptr, nullptr, 0);
    // ---- Layer 2 (pool fused) ----
    mean_kernel<<<meanBlocks, 256, 0, stream>>>(h1, row_start, csr, meanb);
    update_kernel<<<updBlocks, 256, 0, stream>>>(meanb, h1, W2l, b2, W2r, nullptr,
                                                 batch, psum, pcnt, 1);
    // ---- FC ----
    fc_kernel<<<1, 512, 0, stream>>>(psum, pcnt, Wfc, bfc, out);
}

// Round 8
// 209.975 us; speedup vs baseline: 5.0992x; 1.3376x over previous
//
#include <hip/hip_runtime.h>
#include <hip/hip_bf16.h>

#define N_NODES 50000
#define N_EDGES 1000000
#define DIM 64
#define N_GRAPHS 64
#define OUT_DIM 8
#define NBLK_SCAN 196         // ceil(50000/256)
#define NPART 8               // fill: one dst-range partition per XCD
#define PARTBLK 128           // blocks per partition
#define B_STRIDE 8192         // bf16 elements per packed weight layer (128x64)

typedef __attribute__((ext_vector_type(8))) short short8;   // 8 bf16 = 4 VGPR
typedef __attribute__((ext_vector_type(4))) float f32x4;    // MFMA C/D

__device__ __forceinline__ unsigned short f2b(float f) {
    __hip_bfloat16 h = __float2bfloat16(f);
    return *reinterpret_cast<unsigned short*>(&h);
}
__device__ __forceinline__ float b2f(unsigned short u) {
    __hip_bfloat16 h = *reinterpret_cast<__hip_bfloat16*>(&u);
    return __bfloat162float(h);
}

// ---------------------------------------------------------------------------
// CSR build 1: in-degree histogram (int4-vectorized edge reads)
// ---------------------------------------------------------------------------
__global__ void hist_kernel(const int* __restrict__ dst, int* __restrict__ cnt) {
    int e4 = blockIdx.x * blockDim.x + threadIdx.x;
    if (e4 >= N_EDGES / 4) return;
    int4 d = ((const int4*)dst)[e4];
    atomicAdd(&cnt[d.x], 1);
    atomicAdd(&cnt[d.y], 1);
    atomicAdd(&cnt[d.z], 1);
    atomicAdd(&cnt[d.w], 1);
}

__global__ void reduce_kernel(const int* __restrict__ cnt, int* __restrict__ bsum) {
    __shared__ int sd[256];
    int t = threadIdx.x;
    int idx = blockIdx.x * 256 + t;
    sd[t] = (idx < N_NODES) ? cnt[idx] : 0;
    __syncthreads();
    for (int off = 128; off > 0; off >>= 1) {
        if (t < off) sd[t] += sd[t + off];
        __syncthreads();
    }
    if (t == 0) bsum[blockIdx.x] = sd[0];
}

__global__ void scan_bsum_kernel(const int* __restrict__ bsum, int* __restrict__ boff,
                                 int* __restrict__ row_start) {
    __shared__ int sd[256];
    int t = threadIdx.x;
    int v = (t < NBLK_SCAN) ? bsum[t] : 0;
    sd[t] = v;
    __syncthreads();
    for (int off = 1; off < 256; off <<= 1) {
        int u = (t >= off) ? sd[t - off] : 0;
        __syncthreads();
        sd[t] += u;
        __syncthreads();
    }
    if (t < NBLK_SCAN) boff[t] = sd[t] - v;
    if (t == 0) row_start[N_NODES] = N_EDGES;
}

__global__ void scan_write_kernel(const int* __restrict__ cnt, const int* __restrict__ boff,
                                  int* __restrict__ row_start, int* __restrict__ cursor) {
    __shared__ int sd[256];
    int t = threadIdx.x;
    int idx = blockIdx.x * 256 + t;
    int v = (idx < N_NODES) ? cnt[idx] : 0;
    sd[t] = v;
    __syncthreads();
    for (int off = 1; off < 256; off <<= 1) {
        int u = (t >= off) ? sd[t - off] : 0;
        __syncthreads();
        sd[t] += u;
        __syncthreads();
    }
    if (idx < N_NODES) {
        int rs = sd[t] - v + boff[blockIdx.x];
        row_start[idx] = rs;
        cursor[idx] = rs;
    }
}

// XCD-partitioned scatter (R6 fix: csr lines written by exactly one XCD)
__global__ void fill_part_kernel(const int* __restrict__ src, const int* __restrict__ dst,
                                 int* __restrict__ cursor, int* __restrict__ csr) {
    int part = blockIdx.x & (NPART - 1);
    int q = blockIdx.x >> 3;
    int lo = part * (N_NODES / NPART);
    int hi = lo + (N_NODES / NPART);
    for (int e4 = q * blockDim.x + threadIdx.x; e4 < N_EDGES / 4;
         e4 += PARTBLK * blockDim.x) {
        int4 d = ((const int4*)dst)[e4];
        int4 s = ((const int4*)src)[e4];
        if (d.x >= lo && d.x < hi) csr[atomicAdd(&cursor[d.x], 1)] = s.x;
        if (d.y >= lo && d.y < hi) csr[atomicAdd(&cursor[d.y], 1)] = s.y;
        if (d.z >= lo && d.z < hi) csr[atomicAdd(&cursor[d.z], 1)] = s.z;
        if (d.w >= lo && d.w < hi) csr[atomicAdd(&cursor[d.w], 1)] = s.w;
    }
}

// ---------------------------------------------------------------------------
// x (fp32) -> bf16
// ---------------------------------------------------------------------------
__global__ void xcvt_kernel(const float* __restrict__ x, unsigned short* __restrict__ xb) {
    int i = blockIdx.x * 256 + threadIdx.x;
    if (i >= N_NODES * DIM / 4) return;
    float4 v = ((const float4*)x)[i];
    ushort4 u;
    u.x = f2b(v.x); u.y = f2b(v.y); u.z = f2b(v.z); u.w = f2b(v.w);
    ((ushort4*)xb)[i] = u;
}

// ---------------------------------------------------------------------------
// Pre-pack B = [Wl;Wr] (128x64 fp32) into per-lane MFMA fragments, bf16.
// k-map k_local = 8*(lane>>4)+i — a consistent k-relabeling between A and B
// fragments cancels in the MFMA's sum over k, so only M/N mapping matters.
// Bf layout: [layer][ks][nt][lane][8] bf16 = 8192 bf16 (16 KB) per layer.
// (R7 BUG was here: layer stride was 4096 -> layer 2 clobbered layer 1.)
// ---------------------------------------------------------------------------
__global__ void prep_b_kernel(const float* __restrict__ W1l, const float* __restrict__ W1r,
                              const float* __restrict__ W2l, const float* __restrict__ W2r,
                              unsigned short* __restrict__ Bf) {
    int t = blockIdx.x * 256 + threadIdx.x;
    if (t >= 2048) return;
    int layer = t >> 10;
    int rem = t & 1023;
    int ks = rem >> 8;
    int nt = (rem >> 6) & 3;
    int lane = rem & 63;
    int gq = lane >> 4;
    int col = nt * 16 + (lane & 15);
    const float* Wl = layer ? W2l : W1l;
    const float* Wr = layer ? W2r : W1r;
    unsigned short* o = Bf + (size_t)layer * B_STRIDE + ((ks * 4 + nt) * 64 + lane) * 8;
    #pragma unroll
    for (int i = 0; i < 8; ++i) {
        int k = ks * 32 + gq * 8 + i;
        float v = (k < DIM) ? Wl[k * DIM + col] : Wr[(k - DIM) * DIM + col];
        o[i] = f2b(v);
    }
}

// ---------------------------------------------------------------------------
// Neighbor-mean gather, bf16 features (128 B/row). One wave per node;
// 4 groups x 16 lanes, group g loads neighbor (i+g)'s row as ushort4 (8 B x
// 16 lanes = 128 B). fp32 accumulate, shfl_xor reduce, bf16 write.
// ---------------------------------------------------------------------------
__global__ __launch_bounds__(256) void mean_b_kernel(const unsigned short* __restrict__ feat,
                                                     const int* __restrict__ row_start,
                                                     const int* __restrict__ csr,
                                                     unsigned short* __restrict__ mean) {
    int wv = (blockIdx.x * blockDim.x + threadIdx.x) >> 6;
    if (wv >= N_NODES) return;
    int lane = threadIdx.x & 63;
    int grp = lane >> 4;
    int fi = lane & 15;
    int rs = row_start[wv], re = row_start[wv + 1];

    float4 a0 = make_float4(0.f, 0.f, 0.f, 0.f);
    float4 a1 = make_float4(0.f, 0.f, 0.f, 0.f);
    int i = rs;
    for (; i + 8 <= re; i += 8) {
        int s0 = csr[i + grp];
        int s1 = csr[i + 4 + grp];
        ushort4 u0 = ((const ushort4*)(feat + (size_t)s0 * DIM))[fi];
        ushort4 u1 = ((const ushort4*)(feat + (size_t)s1 * DIM))[fi];
        a0.x += b2f(u0.x); a0.y += b2f(u0.y); a0.z += b2f(u0.z); a0.w += b2f(u0.w);
        a1.x += b2f(u1.x); a1.y += b2f(u1.y); a1.z += b2f(u1.z); a1.w += b2f(u1.w);
    }
    if (i + 4 <= re) {
        int s = csr[i + grp];
        ushort4 u = ((const ushort4*)(feat + (size_t)s * DIM))[fi];
        a0.x += b2f(u.x); a0.y += b2f(u.y); a0.z += b2f(u.z); a0.w += b2f(u.w);
        i += 4;
    }
    if (i + grp < re) {
        int s = csr[i + grp];
        ushort4 u = ((const ushort4*)(feat + (size_t)s * DIM))[fi];
        a1.x += b2f(u.x); a1.y += b2f(u.y); a1.z += b2f(u.z); a1.w += b2f(u.w);
    }
    float4 acc = make_float4(a0.x + a1.x, a0.y + a1.y, a0.z + a1.z, a0.w + a1.w);

    acc.x += __shfl_xor(acc.x, 16); acc.y += __shfl_xor(acc.y, 16);
    acc.z += __shfl_xor(acc.z, 16); acc.w += __shfl_xor(acc.w, 16);
    acc.x += __shfl_xor(acc.x, 32); acc.y += __shfl_xor(acc.y, 32);
    acc.z += __shfl_xor(acc.z, 32); acc.w += __shfl_xor(acc.w, 32);

    if (grp == 0) {
        float inv = 1.0f / fmaxf((float)(re - rs), 1.0f);
        ushort4 m;
        m.x = f2b(acc.x * inv); m.y = f2b(acc.y * inv);
        m.z = f2b(acc.z * inv); m.w = f2b(acc.w * inv);
        ((ushort4*)(mean + (size_t)wv * DIM))[fi] = m;
    }
}

// ---------------------------------------------------------------------------
// MFMA update: C[50000x64] = [mean|x] (bf16, K=128) @ Bf + bias, ReLU, bf16.
// One wave = 16 nodes x 64 cols = 4 K-steps x 4 N-tiles = 16 mfma 16x16x32.
// A row = lane&15; A k-chunk = 8*(lane>>4) (matches prep_b's k-map).
// C/D: row = 4*(lane>>4)+reg, col = nt*16 + (lane&15)   [m89-verified].
// ---------------------------------------------------------------------------
__global__ __launch_bounds__(256, 2) void gemm_kernel(
        const unsigned short* __restrict__ Am,   // K 0..63   (mean)
        const unsigned short* __restrict__ Ax,   // K 64..127 (x or h)
        const unsigned short* __restrict__ Bf,   // packed fragments
        const float* __restrict__ bias,
        unsigned short* __restrict__ outb) {
    int wv = (blockIdx.x * blockDim.x + threadIdx.x) >> 6;
    int n0 = wv * 16;
    if (n0 >= N_NODES) return;
    int lane = threadIdx.x & 63;
    int g = lane >> 4;
    int r = lane & 15;

    const short8* Bv = (const short8*)Bf;
    short8 b00 = Bv[ 0 * 64 + lane], b01 = Bv[ 1 * 64 + lane],
           b02 = Bv[ 2 * 64 + lane], b03 = Bv[ 3 * 64 + lane];
    short8 b10 = Bv[ 4 * 64 + lane], b11 = Bv[ 5 * 64 + lane],
           b12 = Bv[ 6 * 64 + lane], b13 = Bv[ 7 * 64 + lane];
    short8 b20 = Bv[ 8 * 64 + lane], b21 = Bv[ 9 * 64 + lane],
           b22 = Bv[10 * 64 + lane], b23 = Bv[11 * 64 + lane];
    short8 b30 = Bv[12 * 64 + lane], b31 = Bv[13 * 64 + lane],
           b32 = Bv[14 * 64 + lane], b33 = Bv[15 * 64 + lane];

    f32x4 acc0 = {0.f, 0.f, 0.f, 0.f}, acc1 = {0.f, 0.f, 0.f, 0.f};
    f32x4 acc2 = {0.f, 0.f, 0.f, 0.f}, acc3 = {0.f, 0.f, 0.f, 0.f};

    const unsigned short* a1p = Am + (size_t)(n0 + r) * DIM + g * 8;
    const unsigned short* a2p = Ax + (size_t)(n0 + r) * DIM + g * 8;

    short8 a;
    a = *(const short8*)(a1p);          // ks=0: k 0..31
    acc0 = __builtin_amdgcn_mfma_f32_16x16x32_bf16(a, b00, acc0, 0, 0, 0);
    acc1 = __builtin_amdgcn_mfma_f32_16x16x32_bf16(a, b01, acc1, 0, 0, 0);
    acc2 = __builtin_amdgcn_mfma_f32_16x16x32_bf16(a, b02, acc2, 0, 0, 0);
    acc3 = __builtin_amdgcn_mfma_f32_16x16x32_bf16(a, b03, acc3, 0, 0, 0);
    a = *(const short8*)(a1p + 32);     // ks=1: k 32..63
    acc0 = __builtin_amdgcn_mfma_f32_16x16x32_bf16(a, b10, acc0, 0, 0, 0);
    acc1 = __builtin_amdgcn_mfma_f32_16x16x32_bf16(a, b11, acc1, 0, 0, 0);
    acc2 = __builtin_amdgcn_mfma_f32_16x16x32_bf16(a, b12, acc2, 0, 0, 0);
    acc3 = __builtin_amdgcn_mfma_f32_16x16x32_bf16(a, b13, acc3, 0, 0, 0);
    a = *(const short8*)(a2p);          // ks=2: k 64..95
    acc0 = __builtin_amdgcn_mfma_f32_16x16x32_bf16(a, b20, acc0, 0, 0, 0);
    acc1 = __builtin_amdgcn_mfma_f32_16x16x32_bf16(a, b21, acc1, 0, 0, 0);
    acc2 = __builtin_amdgcn_mfma_f32_16x16x32_bf16(a, b22, acc2, 0, 0, 0);
    acc3 = __builtin_amdgcn_mfma_f32_16x16x32_bf16(a, b23, acc3, 0, 0, 0);
    a = *(const short8*)(a2p + 32);     // ks=3: k 96..127
    acc0 = __builtin_amdgcn_mfma_f32_16x16x32_bf16(a, b30, acc0, 0, 0, 0);
    acc1 = __builtin_amdgcn_mfma_f32_16x16x32_bf16(a, b31, acc1, 0, 0, 0);
    acc2 = __builtin_amdgcn_mfma_f32_16x16x32_bf16(a, b32, acc2, 0, 0, 0);
    acc3 = __builtin_amdgcn_mfma_f32_16x16x32_bf16(a, b33, acc3, 0, 0, 0);

    int base_row = n0 + 4 * g;
#define EPI(NT, ACC)                                                          \
    {                                                                         \
        float bc = bias[(NT) * 16 + r];                                       \
        _Pragma("unroll")                                                     \
        for (int i = 0; i < 4; ++i) {                                         \
            float v = fmaxf(ACC[i] + bc, 0.0f);                               \
            outb[(size_t)(base_row + i) * DIM + (NT) * 16 + r] = f2b(v);      \
        }                                                                     \
    }
    EPI(0, acc0) EPI(1, acc1) EPI(2, acc2) EPI(3, acc3)
#undef EPI
}

// ---------------------------------------------------------------------------
// Global mean pool — segmented register reduction over bf16 h2 (batch sorted)
// ---------------------------------------------------------------------------
__global__ void pool_b_kernel(const unsigned short* __restrict__ h,
                              const int* __restrict__ batch,
                              float* __restrict__ psum, float* __restrict__ pcnt) {
    int wv = (blockIdx.x * blockDim.x + threadIdx.x) >> 6;
    int start = wv * 16;
    if (start >= N_NODES) return;
    int j = threadIdx.x & 63;
    int end = start + 16;
    if (end > N_NODES) end = N_NODES;

    int g = batch[start];
    float acc = 0.0f, cnt = 0.0f;
    for (int n = start; n < end; ++n) {
        int gn = batch[n];
        if (gn != g) {
            atomicAdd(&psum[g * DIM + j], acc);
            if (j == 0) atomicAdd(&pcnt[g], cnt);
            g = gn; acc = 0.0f; cnt = 0.0f;
        }
        acc += b2f(h[(size_t)n * DIM + j]);
        cnt += 1.0f;
    }
    atomicAdd(&psum[g * DIM + j], acc);
    if (j == 0) atomicAdd(&pcnt[g], cnt);
}

// ---------------------------------------------------------------------------
// Final FC: out[g][o] = (psum[g]/max(cnt,1)) @ Wfc + bfc   (64 x 8, fp32)
// ---------------------------------------------------------------------------
__global__ void fc_kernel(const float* __restrict__ psum,
                          const float* __restrict__ pcnt,
                          const float* __restrict__ Wfc,
                          const float* __restrict__ bfc,
                          float* __restrict__ out) {
    int tid = threadIdx.x;
    if (tid >= N_GRAPHS * OUT_DIM) return;
    int g = tid >> 3;
    int o = tid & 7;
    float inv = 1.0f / fmaxf(pcnt[g], 1.0f);
    float s = bfc[o];
    #pragma unroll
    for (int k = 0; k < DIM; ++k) {
        s += psum[g * DIM + k] * inv * Wfc[k * OUT_DIM + o];
    }
    out[g * OUT_DIM + o] = s;
}

extern "C" void kernel_launch(void* const* d_in, const int* in_sizes, int n_in,
                              void* d_out, int out_size, void* d_ws, size_t ws_size,
                              hipStream_t stream) {
    const float* x   = (const float*)d_in[0];
    const int* ei    = (const int*)d_in[1];
    const int* batch = (const int*)d_in[2];
    const float* W1l = (const float*)d_in[3];
    const float* b1  = (const float*)d_in[4];
    const float* W1r = (const float*)d_in[5];
    const float* W2l = (const float*)d_in[6];
    const float* b2  = (const float*)d_in[7];
    const float* W2r = (const float*)d_in[8];
    const float* Wfc = (const float*)d_in[9];
    const float* bfc = (const float*)d_in[10];
    float* out = (float*)d_out;

    const int* src = ei;
    const int* dst = ei + N_EDGES;

    // workspace layout (~30.3 MB)
    const size_t SZ_BF  = (size_t)N_NODES * DIM * 2;               // 6.4 MB (bf16 feat)
    const size_t SZ_CSR = (size_t)N_EDGES * sizeof(int);           // 4 MB
    const size_t SZ_CNT = ((size_t)(N_NODES + 1) * sizeof(int) + 255) & ~(size_t)255;
    char* ws = (char*)d_ws;
    unsigned short* xb    = (unsigned short*)(ws);
    unsigned short* meanb = (unsigned short*)(ws + SZ_BF);
    unsigned short* h1b   = (unsigned short*)(ws + 2 * SZ_BF);
    unsigned short* h2b   = (unsigned short*)(ws + 3 * SZ_BF);
    int*   csr       = (int*)(ws + 4 * SZ_BF);
    int*   cnt       = (int*)(ws + 4 * SZ_BF + SZ_CSR);
    int*   row_start = (int*)(ws + 4 * SZ_BF + SZ_CSR + SZ_CNT);
    int*   cursor    = (int*)(ws + 4 * SZ_BF + SZ_CSR + 2 * SZ_CNT);
    int*   bsum      = (int*)(ws + 4 * SZ_BF + SZ_CSR + 3 * SZ_CNT);
    int*   boff      = bsum + 256;
    unsigned short* Bf = (unsigned short*)(bsum + 512);            // 2 x 8192 bf16 = 32 KB
    float* psum      = (float*)((char*)Bf + 2 * B_STRIDE * 2);     // after 32 KB
    float* pcnt      = psum + N_GRAPHS * DIM;

    const int edge4Blocks = (N_EDGES / 4 + 255) / 256;             // 977
    const int meanBlocks  = (N_NODES + 3) / 4;                     // 12500
    const int tileWaves   = (N_NODES + 15) / 16;                   // 3125
    const int tileBlocks  = (tileWaves + 3) / 4;                   // 782
    const int xcvtBlocks  = (N_NODES * DIM / 4 + 255) / 256;       // 3125

    hipMemsetAsync(cnt, 0, (size_t)N_NODES * sizeof(int), stream);
    hipMemsetAsync(psum, 0, (size_t)(N_GRAPHS * DIM + N_GRAPHS) * sizeof(float), stream);

    // ---- CSR build ----
    hist_kernel<<<edge4Blocks, 256, 0, stream>>>(dst, cnt);
    reduce_kernel<<<NBLK_SCAN, 256, 0, stream>>>(cnt, bsum);
    scan_bsum_kernel<<<1, 256, 0, stream>>>(bsum, boff, row_start);
    scan_write_kernel<<<NBLK_SCAN, 256, 0, stream>>>(cnt, boff, row_start, cursor);
    fill_part_kernel<<<NPART * PARTBLK, 256, 0, stream>>>(src, dst, cursor, csr);

    // ---- bf16 conversions / weight pre-pack ----
    xcvt_kernel<<<xcvtBlocks, 256, 0, stream>>>(x, xb);
    prep_b_kernel<<<8, 256, 0, stream>>>(W1l, W1r, W2l, W2r, Bf);

    // ---- Layer 1 ----
    mean_b_kernel<<<meanBlocks, 256, 0, stream>>>(xb, row_start, csr, meanb);
    gemm_kernel<<<tileBlocks, 256, 0, stream>>>(meanb, xb, Bf, b1, h1b);
    // ---- Layer 2 ----
    mean_b_kernel<<<meanBlocks, 256, 0, stream>>>(h1b, row_start, csr, meanb);
    gemm_kernel<<<tileBlocks, 256, 0, stream>>>(meanb, h1b, Bf + B_STRIDE, b2, h2b);
    // ---- Pool + FC ----
    pool_b_kernel<<<tileBlocks, 256, 0, stream>>>(h2b, batch, psum, pcnt);
    fc_kernel<<<1, 512, 0, stream>>>(psum, pcnt, Wfc, bfc, out);
}